// Round 6
// baseline (737.014 us; speedup 1.0000x reference)
//
#include <hip/hip_runtime.h>
#include <math.h>

// VQ nearest-codebook, v7: phase-split instrumentation + med3 top-2.
//
// History: v1 662 / v3 697 / v4 855 / v5 592 / v6 589 us. Five structurally
// different kernels, all pipes 10-16%. Cycle accounting cannot explain the
// measured time from known costs (off by >5x). Per the methodology: stop
// hypothesizing, ablate. v7 splits the fused kernel into vq_dist (staging +
// 3-pass split MFMA + top-2 + per-point candidate pair) and vq_finish
// (exact fp32 recheck + idxf + zq gather) so rocprof reports per-phase dur.
// Candidate indices are stashed in zq[p*256+{0,1}] (0..1023 exact in fp32);
// each vq_finish block reads its own rows' stash before overwriting them.
//
// Also: top-2 update now uses v_med3_f32: d2'=med3(d,d1,d2), d1'=min(d,d1)
// -- verified bit-identical to the old branchless ladder (incl. ties),
// ~25% fewer VALU ops in the hottest VALU section.
//
// Unchanged (proven): BM=64 (planes L2-resident, FETCH 170MB), A hi/lo split
// once into XOR-swizzled LDS (conflicts == 0), barrier-free K-loop with
// named double-buffers + sched_barrier fences, 3-pass hh/lh/hl per-cell
// order => bit-identical distances => top-2 + exact recheck => absmax 0.

typedef __attribute__((ext_vector_type(8))) short short8;   // 8 bf16 = 4 VGPR
typedef __attribute__((ext_vector_type(4))) float f32x4;

#define C_DIM 256
#define BM 64     // points per block (dist)
#define KT 128    // codes per kt tile (8 tiles cover K=1024)

__device__ __forceinline__ unsigned short f2bf(float f) {
    unsigned u = __float_as_uint(f);
    return (unsigned short)((u + 0x7fffu + ((u >> 16) & 1u)) >> 16);
}

// cb (K x 256 fp32) -> exact e2, and (if PLANES) bf16 hi/lo planes.
template <bool PLANES>
__global__ __launch_bounds__(256) void vq_prep(
    const float* __restrict__ cb, unsigned short* __restrict__ cbh,
    unsigned short* __restrict__ cbl, float* __restrict__ e2, int K) {
    int wave = threadIdx.x >> 6;
    int lane = threadIdx.x & 63;
    int code = blockIdx.x * 4 + wave;
    if (code >= K) return;
    float4 v = ((const float4*)(cb + (size_t)code * C_DIM))[lane];
    if constexpr (PLANES) {
        unsigned short h[4], l[4];
#pragma unroll
        for (int i = 0; i < 4; ++i) {
            float f = ((const float*)&v)[i];
            unsigned short hh = f2bf(f);
            h[i] = hh;
            l[i] = f2bf(f - __uint_as_float((unsigned)hh << 16));
        }
        *(ushort4*)(cbh + (size_t)code * C_DIM + lane * 4) = make_ushort4(h[0], h[1], h[2], h[3]);
        *(ushort4*)(cbl + (size_t)code * C_DIM + lane * 4) = make_ushort4(l[0], l[1], l[2], l[3]);
    }
    float s = v.x * v.x + v.y * v.y + v.z * v.z + v.w * v.w;
#pragma unroll
    for (int off = 32; off > 0; off >>= 1) s += __shfl_down(s, off, 64);
    if (lane == 0) e2[code] = s;
}

// A fragments (2 m-tiles) from swizzled LDS into named bufs AH/AL, k-step KS.
#define LOADA(AH, AL, KS)                                            \
    {                                                                \
        const int o_ = (KS) * 4 + q;                                 \
        _Pragma("unroll")                                            \
        for (int mt = 0; mt < 2; ++mt) {                             \
            const int ga_ = ((o_ ^ swA[mt]) * 8);                    \
            AH[mt] = *(const short8*)(sXh + arow[mt] + ga_);         \
            AL[mt] = *(const short8*)(sXl + arow[mt] + ga_);         \
        }                                                            \
    }

// B fragments into named buffers DH/DL (compile-time identity), k-step KS.
#define LOADB(DH, DL, KS)                                                      \
    {                                                                          \
        _Pragma("unroll")                                                      \
        for (int nt = 0; nt < 4; ++nt) {                                       \
            if constexpr (PLANES) {                                            \
                DH[nt] = *(const short8*)(bhp + nt * 16 * C_DIM + (KS) * 32);  \
                DL[nt] = *(const short8*)(blp + nt * 16 * C_DIM + (KS) * 32);  \
            } else {                                                           \
                const float* cp_ = cbf + (size_t)nt * 16 * C_DIM + (KS) * 32;  \
                float4 b0_ = ((const float4*)cp_)[0];                          \
                float4 b1_ = ((const float4*)cp_)[1];                          \
                short8 bh_, bl_;                                               \
                _Pragma("unroll")                                              \
                for (int i = 0; i < 8; ++i) {                                  \
                    float f_ = (i < 4) ? ((const float*)&b0_)[i]               \
                                       : ((const float*)&b1_)[i - 4];          \
                    unsigned short hh_ = f2bf(f_);                             \
                    bh_[i] = (short)hh_;                                       \
                    bl_[i] = (short)f2bf(f_ - __uint_as_float((unsigned)hh_ << 16)); \
                }                                                              \
                DH[nt] = bh_;                                                  \
                DL[nt] = bl_;                                                  \
            }                                                                  \
        }                                                                      \
    }

// 3-pass MFMA cluster on (AH,AL) x (BH,BL).
#define MFMA3(AH, AL, BH, BL)                                                  \
    {                                                                          \
        _Pragma("unroll")                                                      \
        for (int mt = 0; mt < 2; ++mt)                                         \
            _Pragma("unroll")                                                  \
            for (int nt = 0; nt < 4; ++nt)                                     \
                acc[mt][nt] = __builtin_amdgcn_mfma_f32_16x16x32_bf16(AH[mt], BH[nt], acc[mt][nt], 0, 0, 0); \
        _Pragma("unroll")                                                      \
        for (int mt = 0; mt < 2; ++mt)                                         \
            _Pragma("unroll")                                                  \
            for (int nt = 0; nt < 4; ++nt)                                     \
                acc[mt][nt] = __builtin_amdgcn_mfma_f32_16x16x32_bf16(AL[mt], BH[nt], acc[mt][nt], 0, 0, 0); \
        _Pragma("unroll")                                                      \
        for (int mt = 0; mt < 2; ++mt)                                         \
            _Pragma("unroll")                                                  \
            for (int nt = 0; nt < 4; ++nt)                                     \
                acc[mt][nt] = __builtin_amdgcn_mfma_f32_16x16x32_bf16(AH[mt], BL[nt], acc[mt][nt], 0, 0, 0); \
    }

template <bool PLANES>
__global__ __launch_bounds__(256, 2) void vq_dist(
    const float* __restrict__ x, const float* __restrict__ cb,
    const unsigned short* __restrict__ cbh, const unsigned short* __restrict__ cbl,
    const float* __restrict__ e2, float* __restrict__ zq, int K) {

    __shared__ char smem[65536];
    short* sXh = (short*)smem;             // [64][256] bf16 hi, granule-swizzled
    short* sXl = (short*)(smem + 32768);   // [64][256] bf16 lo

    const int tid = threadIdx.x;
    const int lane = tid & 63;
    const int w = tid >> 6;          // wave id 0..3
    const int ln = lane & 15;        // column-within-16 (code select)
    const int q = lane >> 4;         // k-octet / point-quad select
    const int wm = (w & 1) * 32;     // wave point-offset (2 point-halves)
    const int wn = (w >> 1) * 64;    // wave code-offset in KT tile (2 code-halves)
    const size_t basep = (size_t)blockIdx.x * BM;

    // ---- split the x tile into LDS once (XOR-swizzled 16B granules) ----
#pragma unroll 1
    for (int j = 0; j < 8; ++j) {
        int gi = j * 256 + tid;        // granule id: 64 rows x 32 granules
        int p = gi >> 5, g = gi & 31;
        const float4* src = (const float4*)(x + (basep + p) * C_DIM + g * 8);
        float4 a0 = src[0], a1 = src[1];
        short8 hi, lo;
#pragma unroll
        for (int i = 0; i < 8; ++i) {
            float f = (i < 4) ? ((const float*)&a0)[i] : ((const float*)&a1)[i - 4];
            unsigned short hh = f2bf(f);
            hi[i] = (short)hh;
            lo[i] = (short)f2bf(f - __uint_as_float((unsigned)hh << 16));
        }
        int dst = p * C_DIM + ((g ^ (p & 31)) * 8);
        *(short8*)(sXh + dst) = hi;
        *(short8*)(sXl + dst) = lo;
    }
    __syncthreads();

    int arow[2], swA[2];
#pragma unroll
    for (int mt = 0; mt < 2; ++mt) {
        int R = wm + mt * 16 + ln;
        arow[mt] = R * C_DIM;
        swA[mt] = R & 31;
    }

    // per-lane top-2 state for 8 point-slots (s = mt*4 + r)
    float d1s[8], d2s[8];
    int c1s[8], c2s[8];
#pragma unroll
    for (int s = 0; s < 8; ++s) { d1s[s] = 1e30f; d2s[s] = 1e30f; c1s[s] = 0; c2s[s] = 1; }

    const int nkt = K / KT;
#pragma unroll 1
    for (int kt = 0; kt < nkt; ++kt) {
        f32x4 acc[2][4];
#pragma unroll
        for (int mt = 0; mt < 2; ++mt)
#pragma unroll
            for (int nt = 0; nt < 4; ++nt)
#pragma unroll
                for (int r = 0; r < 4; ++r) acc[mt][nt][r] = 0.0f;

        int cnv[4];
        float e2v[4];
#pragma unroll
        for (int nt = 0; nt < 4; ++nt) {
            cnv[nt] = kt * KT + wn + nt * 16 + ln;
            e2v[nt] = e2[cnv[nt]];
        }

        const unsigned short* bhp = cbh + ((size_t)kt * KT + wn + ln) * C_DIM + q * 8;
        const unsigned short* blp = cbl + ((size_t)kt * KT + wn + ln) * C_DIM + q * 8;
        const float* cbf = cb + ((size_t)kt * KT + wn + ln) * C_DIM + q * 8;
        (void)cbf;

        short8 B0h[4], B0l[4], B1h[4], B1l[4];
        short8 A0h[2], A0l[2], A1h[2], A1l[2];
        LOADB(B0h, B0l, 0)
        LOADA(A0h, A0l, 0)
#pragma unroll 1
        for (int ksp = 0; ksp < 4; ++ksp) {
            const int k0 = ksp * 2;
            LOADB(B1h, B1l, k0 + 1)
            LOADA(A1h, A1l, k0 + 1)
            __builtin_amdgcn_sched_barrier(0);
            MFMA3(A0h, A0l, B0h, B0l)
            if (ksp < 3) {
                LOADB(B0h, B0l, k0 + 2)
                LOADA(A0h, A0l, k0 + 2)
            }
            __builtin_amdgcn_sched_barrier(0);
            MFMA3(A1h, A1l, B1h, B1l)
        }

        // ---- per-kt top-2 update (med3 form; bit-identical to ladder) ----
#pragma unroll
        for (int mt = 0; mt < 2; ++mt)
#pragma unroll
            for (int nt = 0; nt < 4; ++nt)
#pragma unroll
                for (int r = 0; r < 4; ++r) {
                    float d = fmaf(-2.0f, acc[mt][nt][r], e2v[nt]);
                    int s = mt * 4 + r;
                    int cn = cnv[nt];
                    bool lt1 = d < d1s[s];
                    bool lt2 = d < d2s[s];
                    int tc = lt1 ? c1s[s] : cn;
                    c2s[s] = lt2 ? tc : c2s[s];
                    c1s[s] = lt1 ? cn : c1s[s];
                    d2s[s] = __builtin_amdgcn_fmed3f(d, d1s[s], d2s[s]);
                    d1s[s] = fminf(d, d1s[s]);
                }
    }

    // ---- butterfly top-2 merge across the 16 ln-lanes (codes disjoint) ----
#pragma unroll
    for (int m = 1; m <= 8; m <<= 1) {
#pragma unroll
        for (int s = 0; s < 8; ++s) {
            float od1 = __shfl_xor(d1s[s], m);
            int oc1 = __shfl_xor(c1s[s], m);
            float od2 = __shfl_xor(d2s[s], m);
            int oc2 = __shfl_xor(c2s[s], m);
            bool t = (od1 < d1s[s]) || (od1 == d1s[s] && oc1 < c1s[s]);
            float hd = t ? d1s[s] : od1;   // loser of firsts
            int hc = t ? c1s[s] : oc1;
            float nd1 = t ? od1 : d1s[s];
            int nc1 = t ? oc1 : c1s[s];
            bool u = od2 < d2s[s];
            float md = u ? od2 : d2s[s];   // min of seconds
            int mc = u ? oc2 : c2s[s];
            bool v2 = (hd < md) || (hd == md && hc < mc);
            d2s[s] = v2 ? hd : md;
            c2s[s] = v2 ? hc : mc;
            d1s[s] = nd1;
            c1s[s] = nc1;
        }
    }

    __syncthreads();   // all LDS x-tile reads done; safe to reuse
    float* mD1 = (float*)smem;              // [64][2]
    int* mC1 = (int*)(smem + 512);
    float* mD2 = (float*)(smem + 1024);
    int* mC2 = (int*)(smem + 1536);
    int* sCand = (int*)(smem + 2048);       // [64][2]

    if (ln == 0) {
        int half = w >> 1;
#pragma unroll
        for (int mt = 0; mt < 2; ++mt)
#pragma unroll
            for (int r = 0; r < 4; ++r) {
                int s = mt * 4 + r;
                int p = wm + mt * 16 + q * 4 + r;
                mD1[p * 2 + half] = d1s[s];
                mC1[p * 2 + half] = c1s[s];
                mD2[p * 2 + half] = d2s[s];
                mC2[p * 2 + half] = c2s[s];
            }
    }
    __syncthreads();

    // ---- per-point merge of the two code-halves -> 2 candidates ----
    if (tid < BM) {
        float da1 = mD1[tid * 2], db1 = mD1[tid * 2 + 1];
        int ca1 = mC1[tid * 2], cb1i = mC1[tid * 2 + 1];
        float da2 = mD2[tid * 2], db2 = mD2[tid * 2 + 1];
        int ca2 = mC2[tid * 2], cb2i = mC2[tid * 2 + 1];
        bool t = (db1 < da1) || (db1 == da1 && cb1i < ca1);
        int c1f = t ? cb1i : ca1;
        float xd1 = t ? db2 : da2;
        int xc1 = t ? cb2i : ca2;
        float xd2 = t ? da1 : db1;
        int xc2 = t ? ca1 : cb1i;
        bool u = (xd1 < xd2) || (xd1 == xd2 && xc1 < xc2);
        int c2f = u ? xc1 : xc2;
        sCand[tid * 2] = c1f;
        sCand[tid * 2 + 1] = c2f;
    }
    __syncthreads();

    // ---- stash candidate pair in zq rows (overwritten by vq_finish) ----
    if (tid < 2 * BM)
        zq[(basep + (tid >> 1)) * C_DIM + (tid & 1)] = (float)sCand[tid];
}

// Exact fp32 recheck + idxf + zq gather. One block per 128 points.
__global__ __launch_bounds__(256) void vq_finish(
    const float* __restrict__ x, const float* __restrict__ cb,
    const float* __restrict__ e2, float* __restrict__ zq,
    float* __restrict__ idxf) {

    __shared__ int sCand[256];
    __shared__ int sWin[128];

    const int tid = threadIdx.x;
    const int lane = tid & 63;
    const int w = tid >> 6;
    const size_t basep = (size_t)blockIdx.x * 128;

    // read this block's stashed candidates (before any zq overwrite)
    sCand[tid] = (int)zq[(basep + (tid >> 1)) * C_DIM + (tid & 1)];
    __syncthreads();

    // exact fp32 recheck: one thread per (point, candidate)
    {
        int p = tid >> 1;
        int cc = sCand[tid];
        const float4* xr4 = (const float4*)(x + (basep + p) * C_DIM);
        const float4* cr4 = (const float4*)(cb + (size_t)cc * C_DIM);
        float4 s4 = {0.f, 0.f, 0.f, 0.f};
#pragma unroll 8
        for (int j = 0; j < 64; ++j) {
            float4 a = xr4[j], b = cr4[j];
            s4.x = fmaf(a.x, b.x, s4.x);
            s4.y = fmaf(a.y, b.y, s4.y);
            s4.z = fmaf(a.z, b.z, s4.z);
            s4.w = fmaf(a.w, b.w, s4.w);
        }
        float dot = (s4.x + s4.y) + (s4.z + s4.w);
        float d = fmaf(-2.0f, dot, e2[cc]);
        float od = __shfl_xor(d, 1);
        int oc = __shfl_xor(cc, 1);
        int winc = (d < od || (d == od && cc < oc)) ? cc : oc;
        if ((tid & 1) == 0) {
            sWin[p] = winc;
            idxf[basep + p] = (float)winc;
        }
    }
    __syncthreads();

    // gather winning codebook rows -> zq (cb is L2-hot)
#pragma unroll 4
    for (int i = 0; i < 32; ++i) {
        int p = w * 32 + i;
        int cc = sWin[p];
        float4 v = ((const float4*)(cb + (size_t)cc * C_DIM))[lane];
        ((float4*)(zq + (basep + p) * C_DIM))[lane] = v;
    }
}

extern "C" void kernel_launch(void* const* d_in, const int* in_sizes, int n_in,
                              void* d_out, int out_size, void* d_ws, size_t ws_size,
                              hipStream_t stream) {
    const float* x = (const float*)d_in[0];
    const float* cb = (const float*)d_in[1];
    int N = in_sizes[0] / C_DIM;   // 131072
    int K = in_sizes[1] / C_DIM;   // 1024

    float* zq = (float*)d_out;
    float* idxf = zq + (size_t)N * C_DIM;

    // workspace: e2 (4 KiB, always) + cbh/cbl planes (1 MiB, only if it fits)
    float* e2 = (float*)d_ws;
    unsigned short* cbh = (unsigned short*)((char*)d_ws + 4096);
    unsigned short* cbl = cbh + (size_t)K * C_DIM;
    size_t need = 4096 + (size_t)K * C_DIM * 2 * sizeof(unsigned short);

    if (ws_size >= need) {
        vq_prep<true><<<dim3((K + 3) / 4), dim3(256), 0, stream>>>(cb, cbh, cbl, e2, K);
        vq_dist<true><<<dim3(N / BM), dim3(256), 0, stream>>>(x, cb, cbh, cbl, e2, zq, K);
    } else {
        vq_prep<false><<<dim3((K + 3) / 4), dim3(256), 0, stream>>>(cb, cbh, cbl, e2, K);
        vq_dist<false><<<dim3(N / BM), dim3(256), 0, stream>>>(x, cb, cbh, cbl, e2, zq, K);
    }
    vq_finish<<<dim3(N / 128), dim3(256), 0, stream>>>(x, cb, e2, zq, idxf);
}

// Round 7
// 444.103 us; speedup vs baseline: 1.6596x; 1.6596x over previous
//
#include <hip/hip_runtime.h>
#include <math.h>

// VQ nearest-codebook, v8: m97-style K-loop -- A in registers, B through LDS.
//
// v7 diagnostic: vq_dist alone = 527us; achieved 391 TF = 19% of MFMA ceiling
// = MfmaUtil 16.5% (self-consistent). Root defect since v2: every wave
// streamed its own private B fragments from L2 (16 MB/CU through a thrashing
// 32KB L1, latency hidden only by 2 waves/SIMD). The proven m97 GEMM ladder
// never does this: it stages operands via global_load_lds into LDS shared by
// the block.
//
// v8:
//  - A (this block's 64 points x 256 dims) lives in REGISTERS: per wave
//    16 points -> 16 short8 (64 VGPR) hi/lo, loaded once from global x.
//    Zero A-traffic in the loop.
//  - B staged via global_load_lds (width 16) into LDS, 64-code x 64-dim
//    chunks (16KB hi+lo), double-buffered (32KB), shared by all 4 waves.
//    Linear LDS dest + granule-XOR pre-swizzled SOURCE; reads apply the same
//    XOR -> 2-way bank access == free. One barrier per chunk (m97 pattern).
//  - Per-cell accumulation order unchanged (hh,lh,hl per 32-k step, k
//    ascending) => bit-identical distances. Each wave sees ALL 1024 codes
//    for its own 16 points => code-ascending top-2 (ties -> lowest code =
//    argmin), ln-butterfly merge only, no cross-wave merge.
//  - Epilogue fused: v7's exact recheck formula byte-for-byte + gather.

typedef __attribute__((ext_vector_type(8))) short short8;   // 8 bf16 = 4 VGPR
typedef __attribute__((ext_vector_type(4))) float f32x4;

#define C_DIM 256
#define BM 64     // points per block

__device__ __forceinline__ unsigned short f2bf(float f) {
    unsigned u = __float_as_uint(f);
    return (unsigned short)((u + 0x7fffu + ((u >> 16) & 1u)) >> 16);
}

__device__ __forceinline__ void gll16(const void* g, void* l) {
    __builtin_amdgcn_global_load_lds(
        (const __attribute__((address_space(1))) unsigned int*)g,
        (__attribute__((address_space(3))) unsigned int*)l, 16, 0, 0);
}

// cb (K x 256 fp32) -> exact e2, and (if PLANES) bf16 hi/lo planes.
template <bool PLANES>
__global__ __launch_bounds__(256) void vq_prep(
    const float* __restrict__ cb, unsigned short* __restrict__ cbh,
    unsigned short* __restrict__ cbl, float* __restrict__ e2, int K) {
    int wave = threadIdx.x >> 6;
    int lane = threadIdx.x & 63;
    int code = blockIdx.x * 4 + wave;
    if (code >= K) return;
    float4 v = ((const float4*)(cb + (size_t)code * C_DIM))[lane];
    if constexpr (PLANES) {
        unsigned short h[4], l[4];
#pragma unroll
        for (int i = 0; i < 4; ++i) {
            float f = ((const float*)&v)[i];
            unsigned short hh = f2bf(f);
            h[i] = hh;
            l[i] = f2bf(f - __uint_as_float((unsigned)hh << 16));
        }
        *(ushort4*)(cbh + (size_t)code * C_DIM + lane * 4) = make_ushort4(h[0], h[1], h[2], h[3]);
        *(ushort4*)(cbl + (size_t)code * C_DIM + lane * 4) = make_ushort4(l[0], l[1], l[2], l[3]);
    }
    float s = v.x * v.x + v.y * v.y + v.z * v.z + v.w * v.w;
#pragma unroll
    for (int off = 32; off > 0; off >>= 1) s += __shfl_down(s, off, 64);
    if (lane == 0) e2[code] = s;
}

// Stage chunk CN (64 codes x 64 dims, hi+lo) into LDS buf (CN&1).
// Slot s = j*256 + tid holds (code cl = s>>3, granule-slot gs = s&7);
// source granule g = gs ^ (cl&7)  (inverse-swizzled source, linear dest).
#define STAGE(CN)                                                              \
    {                                                                          \
        const int b_ = (CN) & 1;                                               \
        const int cb0_ = ((CN) >> 2) * 64, db0_ = ((CN) & 3) * 64;             \
        if constexpr (PLANES) {                                                \
            _Pragma("unroll")                                                  \
            for (int j = 0; j < 2; ++j) {                                      \
                int s_ = j * 256 + tid;                                        \
                int cl_ = s_ >> 3, g_ = (s_ & 7) ^ (cl_ & 7);                  \
                const unsigned short* sh_ = cbh + (size_t)(cb0_ + cl_) * C_DIM + db0_ + g_ * 8; \
                const unsigned short* sl_ = cbl + (size_t)(cb0_ + cl_) * C_DIM + db0_ + g_ * 8; \
                gll16(sh_, smem + b_ * 16384 + j * 4096 + w * 1024);           \
                gll16(sl_, smem + b_ * 16384 + 8192 + j * 4096 + w * 1024);    \
            }                                                                  \
        } else {                                                               \
            _Pragma("unroll")                                                  \
            for (int j = 0; j < 2; ++j) {                                      \
                int s_ = j * 256 + tid;                                        \
                int cl_ = s_ >> 3, g_ = (s_ & 7) ^ (cl_ & 7);                  \
                const float* sp_ = cb + (size_t)(cb0_ + cl_) * C_DIM + db0_ + g_ * 8; \
                float4 b0_ = ((const float4*)sp_)[0], b1_ = ((const float4*)sp_)[1]; \
                short8 hi_, lo_;                                               \
                _Pragma("unroll")                                              \
                for (int i = 0; i < 8; ++i) {                                  \
                    float f_ = (i < 4) ? ((const float*)&b0_)[i]               \
                                       : ((const float*)&b1_)[i - 4];          \
                    unsigned short hh_ = f2bf(f_);                             \
                    hi_[i] = (short)hh_;                                       \
                    lo_[i] = (short)f2bf(f_ - __uint_as_float((unsigned)hh_ << 16)); \
                }                                                              \
                *(short8*)(smem + b_ * 16384 + s_ * 16) = hi_;                 \
                *(short8*)(smem + b_ * 16384 + 8192 + s_ * 16) = lo_;          \
            }                                                                  \
        }                                                                      \
    }

// B fragments (4 code-tiles) from LDS chunk buf, k-step KSL (0/1).
#define LOADB(BH, BL, BUF, KSL)                                                \
    {                                                                          \
        _Pragma("unroll")                                                      \
        for (int nt = 0; nt < 4; ++nt) {                                       \
            int cl_ = nt * 16 + ln;                                            \
            int sl_ = ((KSL) * 4 + q) ^ (cl_ & 7);                             \
            BH[nt] = *(const short8*)(smem + (BUF) * 16384 + cl_ * 128 + sl_ * 16); \
            BL[nt] = *(const short8*)(smem + (BUF) * 16384 + 8192 + cl_ * 128 + sl_ * 16); \
        }                                                                      \
    }

// 3-pass MFMA cluster: per-acc order hh -> lh -> hl (bit-exact vs v5-v7).
#define MFMA3(AHF, ALF, BH, BL)                                                \
    {                                                                          \
        _Pragma("unroll")                                                      \
        for (int nt = 0; nt < 4; ++nt)                                         \
            acc[nt] = __builtin_amdgcn_mfma_f32_16x16x32_bf16(AHF, BH[nt], acc[nt], 0, 0, 0); \
        _Pragma("unroll")                                                      \
        for (int nt = 0; nt < 4; ++nt)                                         \
            acc[nt] = __builtin_amdgcn_mfma_f32_16x16x32_bf16(ALF, BH[nt], acc[nt], 0, 0, 0); \
        _Pragma("unroll")                                                      \
        for (int nt = 0; nt < 4; ++nt)                                         \
            acc[nt] = __builtin_amdgcn_mfma_f32_16x16x32_bf16(AHF, BL[nt], acc[nt], 0, 0, 0); \
    }

template <bool PLANES>
__global__ __launch_bounds__(256, 2) void vq_main(
    const float* __restrict__ x, const float* __restrict__ cb,
    const unsigned short* __restrict__ cbh, const unsigned short* __restrict__ cbl,
    const float* __restrict__ e2, float* __restrict__ zq, float* __restrict__ idxf,
    int K) {

    __shared__ char smem[32768];   // B double-buffer: 2 x (8KB hi + 8KB lo)

    const int tid = threadIdx.x;
    const int lane = tid & 63;
    const int w = tid >> 6;          // wave id 0..3; wave owns points w*16..+15
    const int ln = lane & 15;        // code-within-16 / A-row select
    const int q = lane >> 4;         // k-octet select
    const size_t basep = (size_t)blockIdx.x * BM;

    // ---- A fragments: direct from global x, hi/lo split, 8 k-steps ----
    short8 Ah[8], Al[8];
    {
        const float* xr = x + (basep + w * 16 + ln) * C_DIM + q * 8;
#pragma unroll
        for (int ks = 0; ks < 8; ++ks) {
            float4 a0 = ((const float4*)(xr + ks * 32))[0];
            float4 a1 = ((const float4*)(xr + ks * 32))[1];
            short8 hi, lo;
#pragma unroll
            for (int i = 0; i < 8; ++i) {
                float f = (i < 4) ? ((const float*)&a0)[i] : ((const float*)&a1)[i - 4];
                unsigned short hh = f2bf(f);
                hi[i] = (short)hh;
                lo[i] = (short)f2bf(f - __uint_as_float((unsigned)hh << 16));
            }
            Ah[ks] = hi;
            Al[ks] = lo;
        }
    }

    STAGE(0)
    __syncthreads();

    // per-lane top-2 for 4 point-slots (slot r; point = w*16 + q*4 + r)
    float d1s[4], d2s[4];
    int c1s[4], c2s[4];
#pragma unroll
    for (int r = 0; r < 4; ++r) { d1s[r] = 1e30f; d2s[r] = 1e30f; c1s[r] = 0; c2s[r] = 1; }

    const int ncg = K >> 6;   // 16 code-groups of 64
#pragma unroll 1
    for (int cg = 0; cg < ncg; ++cg) {
        f32x4 acc[4];
#pragma unroll
        for (int nt = 0; nt < 4; ++nt)
#pragma unroll
            for (int r = 0; r < 4; ++r) acc[nt][r] = 0.0f;

        int cnv[4];
        float e2v[4];
#pragma unroll
        for (int nt = 0; nt < 4; ++nt) {
            cnv[nt] = cg * 64 + nt * 16 + ln;
            e2v[nt] = e2[cnv[nt]];
        }

#pragma unroll
        for (int dc = 0; dc < 4; ++dc) {
            const int c = cg * 4 + dc;
            const int buf = dc & 1;          // == c & 1 (cg*4 even)
            if (dc < 3) {
                STAGE(c + 1)
            } else if (cg < ncg - 1) {
                STAGE(c + 1)
            }
            short8 Bh[4], Bl[4];
            LOADB(Bh, Bl, buf, 0)
            MFMA3(Ah[2 * dc], Al[2 * dc], Bh, Bl)
            LOADB(Bh, Bl, buf, 1)
            MFMA3(Ah[2 * dc + 1], Al[2 * dc + 1], Bh, Bl)
            __syncthreads();   // stage(c+1) landed; buf reads done before restage
        }

        // ---- per-cg top-2 update (med3 form; v7-verified) ----
#pragma unroll
        for (int nt = 0; nt < 4; ++nt)
#pragma unroll
            for (int r = 0; r < 4; ++r) {
                float d = fmaf(-2.0f, acc[nt][r], e2v[nt]);
                int cn = cnv[nt];
                bool lt1 = d < d1s[r];
                bool lt2 = d < d2s[r];
                int tc = lt1 ? c1s[r] : cn;
                c2s[r] = lt2 ? tc : c2s[r];
                c1s[r] = lt1 ? cn : c1s[r];
                d2s[r] = __builtin_amdgcn_fmed3f(d, d1s[r], d2s[r]);
                d1s[r] = fminf(d, d1s[r]);
            }
    }

    // ---- butterfly top-2 merge across the 16 ln-lanes (codes disjoint) ----
#pragma unroll
    for (int m = 1; m <= 8; m <<= 1) {
#pragma unroll
        for (int r = 0; r < 4; ++r) {
            float od1 = __shfl_xor(d1s[r], m);
            int oc1 = __shfl_xor(c1s[r], m);
            float od2 = __shfl_xor(d2s[r], m);
            int oc2 = __shfl_xor(c2s[r], m);
            bool t = (od1 < d1s[r]) || (od1 == d1s[r] && oc1 < c1s[r]);
            float hd = t ? d1s[r] : od1;   // loser of firsts
            int hc = t ? c1s[r] : oc1;
            float nd1 = t ? od1 : d1s[r];
            int nc1 = t ? oc1 : c1s[r];
            bool u = od2 < d2s[r];
            float md = u ? od2 : d2s[r];   // min of seconds
            int mc = u ? oc2 : c2s[r];
            bool v2 = (hd < md) || (hd == md && hc < mc);
            d2s[r] = v2 ? hd : md;
            c2s[r] = v2 ? hc : mc;
            d1s[r] = nd1;
            c1s[r] = nc1;
        }
    }

    // last dc-loop barrier already fenced LDS reuse
    int* sCand = (int*)smem;          // [64][2]
    int* sWin = (int*)(smem + 512);   // [64]

    if (ln == 0) {
#pragma unroll
        for (int r = 0; r < 4; ++r) {
            int p = w * 16 + q * 4 + r;
            sCand[p * 2] = c1s[r];
            sCand[p * 2 + 1] = c2s[r];
        }
    }
    __syncthreads();

    // ---- exact fp32 recheck (v7 formula byte-for-byte): 1 thread/pair ----
    if (tid < 2 * BM) {
        int p = tid >> 1;
        int cc = sCand[tid];
        const float4* xr4 = (const float4*)(x + (basep + p) * C_DIM);
        const float4* cr4 = (const float4*)(cb + (size_t)cc * C_DIM);
        float4 s4 = {0.f, 0.f, 0.f, 0.f};
#pragma unroll 8
        for (int j = 0; j < 64; ++j) {
            float4 a = xr4[j], b = cr4[j];
            s4.x = fmaf(a.x, b.x, s4.x);
            s4.y = fmaf(a.y, b.y, s4.y);
            s4.z = fmaf(a.z, b.z, s4.z);
            s4.w = fmaf(a.w, b.w, s4.w);
        }
        float dot = (s4.x + s4.y) + (s4.z + s4.w);
        float d = fmaf(-2.0f, dot, e2[cc]);
        float od = __shfl_xor(d, 1);
        int oc = __shfl_xor(cc, 1);
        int winc = (d < od || (d == od && cc < oc)) ? cc : oc;
        if ((tid & 1) == 0) {
            sWin[p] = winc;
            idxf[basep + p] = (float)winc;
        }
    }
    __syncthreads();

    // ---- gather winning codebook rows -> zq (cb is L2-hot) ----
#pragma unroll 2
    for (int pl = 0; pl < 16; ++pl) {
        int p = w * 16 + pl;
        int cc = sWin[p];
        float4 v = ((const float4*)(cb + (size_t)cc * C_DIM))[lane];
        ((float4*)(zq + (basep + p) * C_DIM))[lane] = v;
    }
}

extern "C" void kernel_launch(void* const* d_in, const int* in_sizes, int n_in,
                              void* d_out, int out_size, void* d_ws, size_t ws_size,
                              hipStream_t stream) {
    const float* x = (const float*)d_in[0];
    const float* cb = (const float*)d_in[1];
    int N = in_sizes[0] / C_DIM;   // 131072
    int K = in_sizes[1] / C_DIM;   // 1024

    float* zq = (float*)d_out;
    float* idxf = zq + (size_t)N * C_DIM;

    // workspace: e2 (4 KiB, always) + cbh/cbl planes (1 MiB, only if it fits)
    float* e2 = (float*)d_ws;
    unsigned short* cbh = (unsigned short*)((char*)d_ws + 4096);
    unsigned short* cbl = cbh + (size_t)K * C_DIM;
    size_t need = 4096 + (size_t)K * C_DIM * 2 * sizeof(unsigned short);

    if (ws_size >= need) {
        vq_prep<true><<<dim3((K + 3) / 4), dim3(256), 0, stream>>>(cb, cbh, cbl, e2, K);
        vq_main<true><<<dim3(N / BM), dim3(256), 0, stream>>>(x, cb, cbh, cbl, e2, zq, idxf, K);
    } else {
        vq_prep<false><<<dim3((K + 3) / 4), dim3(256), 0, stream>>>(cb, cbh, cbl, e2, K);
        vq_main<false><<<dim3(N / BM), dim3(256), 0, stream>>>(x, cb, cbh, cbl, e2, zq, idxf, K);
    }
}